// Round 3
// baseline (257.481 us; speedup 1.0000x reference)
//
#include <hip/hip_runtime.h>
#include <hip/hip_bf16.h>
#include <math.h>

#define BB    2
#define NN    4096
#define DIM   512
#define NH    8
#define DH    64
#define NC    1536   // 3*DIM
#define MM    (BB*NN) // 8192

typedef __bf16 bf16x8 __attribute__((ext_vector_type(8)));
typedef __bf16 bf16x4 __attribute__((ext_vector_type(4)));
typedef float  f32x4  __attribute__((ext_vector_type(4)));

#define QSCALE 0.18033688011112042f   // 1/sqrt(64) * log2(e)

__device__ __forceinline__ int swz(int c) { return c ^ (((c >> 3) ^ (c >> 6)) & 7); }
// K-tile swizzle: puts a lane-varying key bit into bank-bit2 (read pattern
// key=(l>>2)*8+4kf+(l&3) made the old swz bit2 lane-invariant -> 2x bank alias).
__device__ __forceinline__ int kswz(int g) { return g ^ ((g >> 3) & 3) ^ (((g >> 6) & 1) << 2); }

__device__ __forceinline__ void gl_lds16(const __hip_bfloat16* g, __bf16* l) {
    __builtin_amdgcn_global_load_lds(
        (const __attribute__((address_space(1))) unsigned int*)g,
        (__attribute__((address_space(3))) unsigned int*)l, 16, 0, 0);
}

__device__ __forceinline__ int sniff(const unsigned short* x) {
    unsigned short v = x[2 * (threadIdx.x & 63)];
    int e = (v >> 7) & 0xFF;
    unsigned long long m = __ballot(e >= 110 && e <= 140);
    return __popcll(m) >= 48;
}

__device__ __forceinline__ f32x4 mfma32(bf16x8 a, bf16x8 b, f32x4 c) {
    return __builtin_amdgcn_mfma_f32_16x16x32_bf16(a, b, c, 0, 0, 0);
}

// ---------------- prep: X->bf16 (fp32 mode only), W->WT tiled transpose, bias->f32
__global__ __launch_bounds__(256) void prep_kernel(
    const void* __restrict__ xin, const void* __restrict__ win,
    const void* __restrict__ bin,
    __hip_bfloat16* __restrict__ Xb, __hip_bfloat16* __restrict__ WT,
    float* __restrict__ Bf)
{
    __shared__ __bf16 tile[64][68];
    int bfmode = sniff((const unsigned short*)xin);
    int bid = blockIdx.x;
    int t = threadIdx.x;
    if (bid < 2048) {
        if (bfmode) return;
        int i = (bid * 256 + t) * 8;
        const float* xf = (const float*)xin + i;
        bf16x8 v;
        for (int j = 0; j < 8; j++) v[j] = (__bf16)xf[j];
        *(bf16x8*)(Xb + i) = v;
    } else if (bid < 2048 + 192) {
        int tl = bid - 2048;
        int kt = tl / 24, nt = tl % 24;
        int tx = t & 63, tyq = t >> 6;
        for (int r = 0; r < 16; r++) {
            int kl = r * 4 + tyq;
            int gi = (kt * 64 + kl) * NC + nt * 64 + tx;
            float v = bfmode ? __bfloat162float(((const __hip_bfloat16*)win)[gi])
                             : ((const float*)win)[gi];
            tile[kl][tx] = (__bf16)v;
        }
        __syncthreads();
        for (int r = 0; r < 16; r++) {
            int nl = r * 4 + tyq;
            WT[(size_t)(nt * 64 + nl) * DIM + kt * 64 + tx] = (__hip_bfloat16)(float)tile[tx][nl];
        }
    } else {
        int i = (bid - 2048 - 192) * 256 + t;
        if (i < NC)
            Bf[i] = bfmode ? __bfloat162float(((const __hip_bfloat16*)bin)[i])
                           : ((const float*)bin)[i];
    }
}

// ---------------- QKV GEMM (unchanged) ----------------
__global__ __launch_bounds__(256, 3) void qkv_gemm(
    const unsigned short* __restrict__ xs,
    const __hip_bfloat16* __restrict__ Xb,
    const __hip_bfloat16* __restrict__ WT,
    const float* __restrict__ Bf,
    __hip_bfloat16* __restrict__ Qb,
    __hip_bfloat16* __restrict__ Kb,
    __hip_bfloat16* __restrict__ Vt)
{
    __shared__ __align__(16) __bf16 smem[16384];
    __bf16* Xs = smem;
    __bf16* Ws = smem + 8192;

    int bfmode = sniff(xs);
    const __hip_bfloat16* X = bfmode ? (const __hip_bfloat16*)xs : Xb;

    int wave = threadIdx.x >> 6, lane = threadIdx.x & 63;
    int lane16 = lane & 15, quad = lane >> 4;
    int bm = blockIdx.x / 12, bn = blockIdx.x % 12;
    int m0b = bm * 128, n0b = bn * 128;
    int wm = wave >> 1, wn = wave & 1;
    int m0 = m0b + wm * 64, n0 = n0b + wn * 64;

    int xgo[2], sbase[2];
    for (int j = 0; j < 2; j++) {
        int p = (wave * 2 + j) * 64 + lane;
        int g = swz(p);
        xgo[j] = (g >> 2) * DIM + (g & 3) * 8;
        sbase[j] = (wave * 2 + j) * 512;
    }
    int aoff[4], boff[4];
    for (int mi = 0; mi < 4; mi++)
        aoff[mi] = swz((wm * 64 + mi * 16 + lane16) * 4 + quad) * 8;
    for (int ni = 0; ni < 4; ni++)
        boff[ni] = swz((wn * 64 + ni * 16 + lane16) * 4 + quad) * 8;

    const __hip_bfloat16* Xg = X  + (size_t)m0b * DIM;
    const __hip_bfloat16* Wg = WT + (size_t)n0b * DIM;

    for (int j = 0; j < 2; j++) {
        gl_lds16(Xg + xgo[j], &Xs[sbase[j]]);
        gl_lds16(Wg + xgo[j], &Ws[sbase[j]]);
    }
    __syncthreads();

    f32x4 acc[4][4] = {};
    for (int k0 = 0; k0 < DIM; k0 += 32) {
        int cur = (k0 >> 5) & 1, nbuf = cur ^ 1;
        int k1 = (k0 + 32) & (DIM - 1);
        for (int j = 0; j < 2; j++) {
            gl_lds16(Xg + k1 + xgo[j], &Xs[nbuf * 4096 + sbase[j]]);
            gl_lds16(Wg + k1 + xgo[j], &Ws[nbuf * 4096 + sbase[j]]);
        }
        bf16x8 a[4], b[4];
        for (int mi = 0; mi < 4; mi++) a[mi] = *(const bf16x8*)&Xs[cur * 4096 + aoff[mi]];
        for (int ni = 0; ni < 4; ni++) b[ni] = *(const bf16x8*)&Ws[cur * 4096 + boff[ni]];
        for (int mi = 0; mi < 4; mi++)
            for (int ni = 0; ni < 4; ni++)
                acc[mi][ni] = mfma32(a[mi], b[ni], acc[mi][ni]);
        __syncthreads();
    }
    __bf16* epi = smem + wave * 4096;

    int sec = n0b >> 9;
    int bidx = m0b >> 12;
    if (sec == 1) {
        for (int ni = 0; ni < 4; ni++) {
            int nloc = ni * 16 + lane16;
            float bv = Bf[n0 + nloc];
            for (int mi = 0; mi < 4; mi++) {
                bf16x4 pk;
                for (int r = 0; r < 4; r++) pk[r] = (__bf16)(acc[mi][ni][r] + bv);
                int idx = swz(nloc * 8 + mi * 2 + (quad >> 1)) * 8 + (quad & 1) * 4;
                *(bf16x4*)&epi[idx] = pk;
            }
        }
        int hl = (n0 - 512) >> 6;
        int mbase = m0b - bidx * NN + wm * 64;
        for (int p = 0; p < 8; p++) {
            int n = p * 8 + (lane >> 3), mc = lane & 7;
            bf16x8 vv = *(const bf16x8*)&epi[swz(n * 8 + mc) * 8];
            *(bf16x8*)(Vt + ((size_t)(bidx * 8 + hl) * 64 + n) * NN + mbase + mc * 8) = vv;
        }
    } else {
        bool isQ = (sec == 0);
        int h = (n0 & 511) >> 6;
        for (int mi = 0; mi < 4; mi++) {
            for (int ni = 0; ni < 4; ni++) {
                float bv = Bf[n0 + ni * 16 + lane16];
                int dl = ni * 16 + lane16;
                for (int r = 0; r < 4; r++) {
                    int row = mi * 16 + quad * 4 + r;
                    float v = acc[mi][ni][r] + bv;
                    if (isQ) v *= QSCALE;
                    epi[swz(row * 8 + (dl >> 3)) * 8 + (dl & 7)] = (__bf16)v;
                }
            }
        }
        __hip_bfloat16* dst = isQ ? Qb : Kb;
        int bh = bidx * 8 + h;
        int mbase = m0 - bidx * NN;
        for (int p = 0; p < 8; p++) {
            int row = p * 8 + (lane >> 3), dc = lane & 7;
            bf16x8 vv = *(const bf16x8*)&epi[swz(row * 8 + dc) * 8];
            *(bf16x8*)(dst + ((size_t)bh * NN + mbase + row) * DH + dc * 8) = vv;
        }
    }
}

// ---------------- Fused attention: key-split x2 in-block, V direct from L2 --
// 4 waves/block: waves {0,1} own key-half 0, waves {2,3} own key-half 1, same
// 64 q rows. K tiles staged via global_load_lds (kswz'd, KVBLK=32, dbuf).
// V is NOT staged: each wave register-loads its 64x32 V tile directly from
// global (per-XCD working set 2 heads x 1.5MB < 4MB L2; intra-block 2-wave
// reuse served by L1). V is double-buffered in regs via manual 2x unroll
// (static indexing), prefetched a full step ahead under the QK^T MFMAs.
// Epilogue combines halves' unnormalized O/l in LDS and stores final output.
__global__ __launch_bounds__(256, 4) void attn_fused(
    const __hip_bfloat16* __restrict__ Qb,   // [16][4096][64], pre-scaled
    const __hip_bfloat16* __restrict__ Kb,   // [16][4096][64]
    const __hip_bfloat16* __restrict__ Vt,   // [16][64][4096]
    void* __restrict__ OutV,                 // [2][4096][512] bf16 or fp32
    const unsigned short* __restrict__ xs)
{
    __shared__ __align__(16) __bf16 smem[16384];   // 32 KB (epilogue needs 17.7KB)

    int bfmode = sniff(xs);
    int wave = threadIdx.x >> 6, lane = threadIdx.x & 63;
    int lane16 = lane & 15, quad = lane >> 4;
    int half = wave >> 1, qw = wave & 1;

    // XCD swizzle: 1024 blocks, 128 per XCD = 2 whole heads per XCD L2.
    int orig = blockIdx.x;
    int nbid = (orig & 7) * 128 + (orig >> 3);
    int bh = nbid >> 6;
    int qt = nbid & 63;
    int q0 = qt * 64 + qw * 32;
    int khbase = half * 2048;

    __bf16* Kst = smem + half * 4096;          // [2][2048] dbuf per half (16KB total)

    const __hip_bfloat16* Qh = Qb + (size_t)bh * NN * DH;
    const __hip_bfloat16* Kh = Kb + (size_t)bh * NN * DH;
    const __hip_bfloat16* Vh = Vt + (size_t)bh * DH * NN;

    // Q as B-operand (loop-invariant)
    bf16x8 bq[2][2];
    #pragma unroll
    for (int qf = 0; qf < 2; qf++)
        #pragma unroll
        for (int kc = 0; kc < 2; kc++)
            bq[qf][kc] = *(const bf16x8*)(Qh + (size_t)(q0 + qf * 16 + lane16) * DH + kc * 32 + quad * 8);

    // K staging map: 32x64 tile = 256 granules (8/row), kswz
    int kgo[2], sbase[2];
    #pragma unroll
    for (int j = 0; j < 2; j++) {
        int p = (qw * 2 + j) * 64 + lane;
        int gk = kswz(p);
        kgo[j] = (gk >> 3) * DH + (gk & 7) * 8;
        sbase[j] = (qw * 2 + j) * 512;
    }
    // K A-frag offsets with key permutation sigma (32-key restriction)
    int koff[2][2];
    #pragma unroll
    for (int kf = 0; kf < 2; kf++) {
        int key = (lane16 >> 2) * 8 + 4 * kf + (lane16 & 3);
        #pragma unroll
        for (int kc = 0; kc < 2; kc++)
            koff[kf][kc] = kswz(key * 8 + kc * 4 + quad) * 8;
    }
    // V direct-load base: row d = dt*16+lane16, keys quad*8..+7 at tile k
    const __hip_bfloat16* Vp = Vh + (size_t)lane16 * NN + quad * 8 + khbase;

    for (int j = 0; j < 2; j++)
        gl_lds16(Kh + (size_t)khbase * DH + kgo[j], &Kst[sbase[j]]);

    bf16x8 avA[4], avB[4];
    #pragma unroll
    for (int dt = 0; dt < 4; dt++)
        avA[dt] = *(const bf16x8*)(Vp + (size_t)dt * 16 * NN);
    __syncthreads();

    bf16x8 ones8;
    #pragma unroll
    for (int j = 0; j < 8; j++) ones8[j] = (__bf16)1.0f;
    f32x4 o[4][2] = {};    // O^T[d-frag dt][q-frag qf]
    f32x4 ol[2] = {};      // l[q]

#define AT_STEP(CUR, AVC, AVN, IT)                                                 \
    {                                                                              \
        int kn = ((IT) + 1) & 63;                                                  \
        int k1 = khbase + kn * 32;                                                 \
        for (int j = 0; j < 2; j++)                                                \
            gl_lds16(Kh + (size_t)k1 * DH + kgo[j],                                \
                     &Kst[((CUR) ^ 1) * 2048 + sbase[j]]);                         \
        _Pragma("unroll")                                                          \
        for (int dt = 0; dt < 4; dt++)                                             \
            AVN[dt] = *(const bf16x8*)(Vp + (size_t)dt * 16 * NN + kn * 32);       \
        bf16x8 ka[2][2];                                                           \
        _Pragma("unroll")                                                          \
        for (int kf = 0; kf < 2; kf++)                                             \
            _Pragma("unroll")                                                      \
            for (int kc = 0; kc < 2; kc++)                                         \
                ka[kf][kc] = *(const bf16x8*)&Kst[(CUR) * 2048 + koff[kf][kc]];    \
        f32x4 s[2][2];                                                             \
        _Pragma("unroll")                                                          \
        for (int kf = 0; kf < 2; kf++)                                             \
            _Pragma("unroll")                                                      \
            for (int qf = 0; qf < 2; qf++) {                                       \
                f32x4 t = {};                                                      \
                t = mfma32(ka[kf][0], bq[qf][0], t);                               \
                t = mfma32(ka[kf][1], bq[qf][1], t);                               \
                s[kf][qf] = t;                                                     \
            }                                                                      \
        bf16x4 pt[2][2];                                                           \
        _Pragma("unroll")                                                          \
        for (int kf = 0; kf < 2; kf++)                                             \
            _Pragma("unroll")                                                      \
            for (int qf = 0; qf < 2; qf++)                                         \
                _Pragma("unroll")                                                  \
                for (int r = 0; r < 4; r++)                                        \
                    pt[kf][qf][r] = (__bf16)__builtin_amdgcn_exp2f(s[kf][qf][r]);  \
        _Pragma("unroll")                                                          \
        for (int qf = 0; qf < 2; qf++) {                                           \
            bf16x8 pb = __builtin_shufflevector(pt[0][qf], pt[1][qf],              \
                                                0, 1, 2, 3, 4, 5, 6, 7);           \
            _Pragma("unroll")                                                      \
            for (int dt = 0; dt < 4; dt++)                                         \
                o[dt][qf] = mfma32(AVC[dt], pb, o[dt][qf]);                        \
            ol[qf] = mfma32(ones8, pb, ol[qf]);                                    \
        }                                                                          \
        __syncthreads();                                                           \
    }

    for (int it = 0; it < 64; it += 2) {
        AT_STEP(0, avA, avB, it);
        AT_STEP(1, avB, avA, it + 1);
    }
#undef AT_STEP

    // ---- epilogue: cross-half combine in LDS, then normalized store --------
    // All DMA drained by the loop's final barrier; smem is reusable.
    float* Osh = (float*)smem;            // [2][32][68] f32, pad 68 -> 2-way max
    float* lsh = Osh + 2 * 32 * 68;       // [2][32]
    if (half == 1) {
        #pragma unroll
        for (int qf = 0; qf < 2; qf++) {
            #pragma unroll
            for (int dt = 0; dt < 4; dt++)
                *(f32x4*)&Osh[(qw * 32 + qf * 16 + lane16) * 68 + dt * 16 + quad * 4] = o[dt][qf];
            if (quad == 0) lsh[qw * 32 + qf * 16 + lane16] = ol[qf][0];
        }
    }
    __syncthreads();
    if (half == 0) {
        // epi region starts past Osh+lsh (17664 B -> bf16 index 8832)
        __bf16* epi = smem + 8832 + qw * 2048;
        #pragma unroll
        for (int qf = 0; qf < 2; qf++) {
            float l = ol[qf][0] + lsh[qw * 32 + qf * 16 + lane16];
            float rinv = 1.0f / l;
            #pragma unroll
            for (int dt = 0; dt < 4; dt++) {
                f32x4 po = *(const f32x4*)&Osh[(qw * 32 + qf * 16 + lane16) * 68 + dt * 16 + quad * 4];
                #pragma unroll
                for (int r = 0; r < 4; r++) {
                    int d = dt * 16 + quad * 4 + r;
                    int row = qf * 16 + lane16;
                    epi[swz(row * 8 + (d >> 3)) * 8 + (d & 7)] = (__bf16)((o[dt][qf][r] + po[r]) * rinv);
                }
            }
        }
        int bidx = bh >> 3, h = bh & 7;
        for (int p = 0; p < 4; p++) {
            int row = p * 8 + (lane >> 3), mc = lane & 7;
            bf16x8 vv = *(const bf16x8*)&epi[swz(row * 8 + mc) * 8];
            size_t base = ((size_t)bidx * NN + q0 + row) * DIM + h * 64 + mc * 8;
            if (bfmode) {
                *(bf16x8*)((__hip_bfloat16*)OutV + base) = vv;
            } else {
                float* op = (float*)OutV + base;
                f32x4 f0, f1;
                for (int j = 0; j < 4; j++) { f0[j] = (float)vv[j]; f1[j] = (float)vv[4 + j]; }
                *(f32x4*)op = f0;
                *(f32x4*)(op + 4) = f1;
            }
        }
    }
}

extern "C" void kernel_launch(void* const* d_in, const int* in_sizes, int n_in,
                              void* d_out, int out_size, void* d_ws, size_t ws_size,
                              hipStream_t stream) {
    char* ws = (char*)d_ws;
    __hip_bfloat16* Qb = (__hip_bfloat16*)ws;
    __hip_bfloat16* Kb = Qb + (size_t)BB * NH * NN * DH;
    __hip_bfloat16* Vt = Kb + (size_t)BB * NH * NN * DH;
    __hip_bfloat16* WT = Vt + (size_t)BB * NH * NN * DH;
    __hip_bfloat16* Xb = WT + (size_t)NC * DIM;
    float* Bf = (float*)(Xb + (size_t)MM * DIM);

    prep_kernel<<<2048 + 192 + 6, 256, 0, stream>>>(d_in[0], d_in[1], d_in[2], Xb, WT, Bf);
    qkv_gemm<<<(MM / 128) * (NC / 128), 256, 0, stream>>>(
        (const unsigned short*)d_in[0], Xb, WT, Bf, Qb, Kb, Vt);
    attn_fused<<<1024, 256, 0, stream>>>(Qb, Kb, Vt, d_out, (const unsigned short*)d_in[0]);
}

// Round 4
// 176.189 us; speedup vs baseline: 1.4614x; 1.4614x over previous
//
#include <hip/hip_runtime.h>
#include <hip/hip_bf16.h>
#include <math.h>

#define BB    2
#define NN    4096
#define DIM   512
#define NH    8
#define DH    64
#define NC    1536   // 3*DIM
#define MM    (BB*NN) // 8192

typedef __bf16 bf16x8 __attribute__((ext_vector_type(8)));
typedef __bf16 bf16x4 __attribute__((ext_vector_type(4)));
typedef float  f32x4  __attribute__((ext_vector_type(4)));

#define QSCALE 0.18033688011112042f   // 1/sqrt(64) * log2(e)

__device__ __forceinline__ int swz(int c) { return c ^ (((c >> 3) ^ (c >> 6)) & 7); }
// K-tile swizzle: puts a lane-varying key bit into bank-bit2 (read pattern
// key=(l>>2)*8+4kf+(l&3) made the old swz bit2 lane-invariant -> 2x bank alias).
__device__ __forceinline__ int kswz(int g) { return g ^ ((g >> 3) & 3) ^ (((g >> 6) & 1) << 2); }

__device__ __forceinline__ void gl_lds16(const __hip_bfloat16* g, __bf16* l) {
    __builtin_amdgcn_global_load_lds(
        (const __attribute__((address_space(1))) unsigned int*)g,
        (__attribute__((address_space(3))) unsigned int*)l, 16, 0, 0);
}

__device__ __forceinline__ int sniff(const unsigned short* x) {
    unsigned short v = x[2 * (threadIdx.x & 63)];
    int e = (v >> 7) & 0xFF;
    unsigned long long m = __ballot(e >= 110 && e <= 140);
    return __popcll(m) >= 48;
}

__device__ __forceinline__ f32x4 mfma32(bf16x8 a, bf16x8 b, f32x4 c) {
    return __builtin_amdgcn_mfma_f32_16x16x32_bf16(a, b, c, 0, 0, 0);
}

// ---------------- prep: X->bf16 (fp32 mode only), W->WT tiled transpose, bias->f32
__global__ __launch_bounds__(256) void prep_kernel(
    const void* __restrict__ xin, const void* __restrict__ win,
    const void* __restrict__ bin,
    __hip_bfloat16* __restrict__ Xb, __hip_bfloat16* __restrict__ WT,
    float* __restrict__ Bf)
{
    __shared__ __bf16 tile[64][68];
    int bfmode = sniff((const unsigned short*)xin);
    int bid = blockIdx.x;
    int t = threadIdx.x;
    if (bid < 2048) {
        if (bfmode) return;
        int i = (bid * 256 + t) * 8;
        const float* xf = (const float*)xin + i;
        bf16x8 v;
        for (int j = 0; j < 8; j++) v[j] = (__bf16)xf[j];
        *(bf16x8*)(Xb + i) = v;
    } else if (bid < 2048 + 192) {
        int tl = bid - 2048;
        int kt = tl / 24, nt = tl % 24;
        int tx = t & 63, tyq = t >> 6;
        for (int r = 0; r < 16; r++) {
            int kl = r * 4 + tyq;
            int gi = (kt * 64 + kl) * NC + nt * 64 + tx;
            float v = bfmode ? __bfloat162float(((const __hip_bfloat16*)win)[gi])
                             : ((const float*)win)[gi];
            tile[kl][tx] = (__bf16)v;
        }
        __syncthreads();
        for (int r = 0; r < 16; r++) {
            int nl = r * 4 + tyq;
            WT[(size_t)(nt * 64 + nl) * DIM + kt * 64 + tx] = (__hip_bfloat16)(float)tile[tx][nl];
        }
    } else {
        int i = (bid - 2048 - 192) * 256 + t;
        if (i < NC)
            Bf[i] = bfmode ? __bfloat162float(((const __hip_bfloat16*)bin)[i])
                           : ((const float*)bin)[i];
    }
}

// ---------------- QKV GEMM (unchanged) ----------------
__global__ __launch_bounds__(256, 3) void qkv_gemm(
    const unsigned short* __restrict__ xs,
    const __hip_bfloat16* __restrict__ Xb,
    const __hip_bfloat16* __restrict__ WT,
    const float* __restrict__ Bf,
    __hip_bfloat16* __restrict__ Qb,
    __hip_bfloat16* __restrict__ Kb,
    __hip_bfloat16* __restrict__ Vt)
{
    __shared__ __align__(16) __bf16 smem[16384];
    __bf16* Xs = smem;
    __bf16* Ws = smem + 8192;

    int bfmode = sniff(xs);
    const __hip_bfloat16* X = bfmode ? (const __hip_bfloat16*)xs : Xb;

    int wave = threadIdx.x >> 6, lane = threadIdx.x & 63;
    int lane16 = lane & 15, quad = lane >> 4;
    int bm = blockIdx.x / 12, bn = blockIdx.x % 12;
    int m0b = bm * 128, n0b = bn * 128;
    int wm = wave >> 1, wn = wave & 1;
    int m0 = m0b + wm * 64, n0 = n0b + wn * 64;

    int xgo[2], sbase[2];
    for (int j = 0; j < 2; j++) {
        int p = (wave * 2 + j) * 64 + lane;
        int g = swz(p);
        xgo[j] = (g >> 2) * DIM + (g & 3) * 8;
        sbase[j] = (wave * 2 + j) * 512;
    }
    int aoff[4], boff[4];
    for (int mi = 0; mi < 4; mi++)
        aoff[mi] = swz((wm * 64 + mi * 16 + lane16) * 4 + quad) * 8;
    for (int ni = 0; ni < 4; ni++)
        boff[ni] = swz((wn * 64 + ni * 16 + lane16) * 4 + quad) * 8;

    const __hip_bfloat16* Xg = X  + (size_t)m0b * DIM;
    const __hip_bfloat16* Wg = WT + (size_t)n0b * DIM;

    for (int j = 0; j < 2; j++) {
        gl_lds16(Xg + xgo[j], &Xs[sbase[j]]);
        gl_lds16(Wg + xgo[j], &Ws[sbase[j]]);
    }
    __syncthreads();

    f32x4 acc[4][4] = {};
    for (int k0 = 0; k0 < DIM; k0 += 32) {
        int cur = (k0 >> 5) & 1, nbuf = cur ^ 1;
        int k1 = (k0 + 32) & (DIM - 1);
        for (int j = 0; j < 2; j++) {
            gl_lds16(Xg + k1 + xgo[j], &Xs[nbuf * 4096 + sbase[j]]);
            gl_lds16(Wg + k1 + xgo[j], &Ws[nbuf * 4096 + sbase[j]]);
        }
        bf16x8 a[4], b[4];
        for (int mi = 0; mi < 4; mi++) a[mi] = *(const bf16x8*)&Xs[cur * 4096 + aoff[mi]];
        for (int ni = 0; ni < 4; ni++) b[ni] = *(const bf16x8*)&Ws[cur * 4096 + boff[ni]];
        for (int mi = 0; mi < 4; mi++)
            for (int ni = 0; ni < 4; ni++)
                acc[mi][ni] = mfma32(a[mi], b[ni], acc[mi][ni]);
        __syncthreads();
    }
    __bf16* epi = smem + wave * 4096;

    int sec = n0b >> 9;
    int bidx = m0b >> 12;
    if (sec == 1) {
        for (int ni = 0; ni < 4; ni++) {
            int nloc = ni * 16 + lane16;
            float bv = Bf[n0 + nloc];
            for (int mi = 0; mi < 4; mi++) {
                bf16x4 pk;
                for (int r = 0; r < 4; r++) pk[r] = (__bf16)(acc[mi][ni][r] + bv);
                int idx = swz(nloc * 8 + mi * 2 + (quad >> 1)) * 8 + (quad & 1) * 4;
                *(bf16x4*)&epi[idx] = pk;
            }
        }
        int hl = (n0 - 512) >> 6;
        int mbase = m0b - bidx * NN + wm * 64;
        for (int p = 0; p < 8; p++) {
            int n = p * 8 + (lane >> 3), mc = lane & 7;
            bf16x8 vv = *(const bf16x8*)&epi[swz(n * 8 + mc) * 8];
            *(bf16x8*)(Vt + ((size_t)(bidx * 8 + hl) * 64 + n) * NN + mbase + mc * 8) = vv;
        }
    } else {
        bool isQ = (sec == 0);
        int h = (n0 & 511) >> 6;
        for (int mi = 0; mi < 4; mi++) {
            for (int ni = 0; ni < 4; ni++) {
                float bv = Bf[n0 + ni * 16 + lane16];
                int dl = ni * 16 + lane16;
                for (int r = 0; r < 4; r++) {
                    int row = mi * 16 + quad * 4 + r;
                    float v = acc[mi][ni][r] + bv;
                    if (isQ) v *= QSCALE;
                    epi[swz(row * 8 + (dl >> 3)) * 8 + (dl & 7)] = (__bf16)v;
                }
            }
        }
        __hip_bfloat16* dst = isQ ? Qb : Kb;
        int bh = bidx * 8 + h;
        int mbase = m0 - bidx * NN;
        for (int p = 0; p < 8; p++) {
            int row = p * 8 + (lane >> 3), dc = lane & 7;
            bf16x8 vv = *(const bf16x8*)&epi[swz(row * 8 + dc) * 8];
            *(bf16x8*)(dst + ((size_t)bh * NN + mbase + row) * DH + dc * 8) = vv;
        }
    }
}

// ---------------- Fused attention: 64 q rows PER WAVE, key-split x2 ---------
// Block = 128 q rows x 4096 keys, 4 waves: half = wave>>1 picks key half,
// qw = wave&1 picks 64-q subtile. Exactly ONE wave reads each K/V LDS tile
// (no duplicate ds_reads -> LDS pipe traffic halved vs the 32q/wave version);
// MFMA:ds_read ratio doubles to 4.5. Same KVBLK=32, kswz'd K, gl_lds dbuf,
// one __syncthreads per step. 2 blocks/CU (512 blocks), 8 waves/CU.
// Epilogue combines halves' unnormalized O/l in LDS, writes final output.
__global__ __launch_bounds__(256, 2) void attn_fused(
    const __hip_bfloat16* __restrict__ Qb,   // [16][4096][64], pre-scaled
    const __hip_bfloat16* __restrict__ Kb,   // [16][4096][64]
    const __hip_bfloat16* __restrict__ Vt,   // [16][64][4096]
    void* __restrict__ OutV,                 // [2][4096][512] bf16 or fp32
    const unsigned short* __restrict__ xs)
{
    // loop: [half][ Kdbuf 2x2048 | Vdbuf 2x2048 ] = 16384 elems (32 KB)
    // epilogue: Osh 128x68 f32 + lsh 128 f32 (17664 elems) + epi 2x4096
    __shared__ __align__(16) __bf16 smem[26624];   // 53.25 KB

    int bfmode = sniff(xs);
    int wave = threadIdx.x >> 6, lane = threadIdx.x & 63;
    int lane16 = lane & 15, quad = lane >> 4;
    int half = wave >> 1, qw = wave & 1;

    // XCD swizzle: 512 blocks, 64 per XCD = 2 whole heads per XCD L2.
    int orig = blockIdx.x;
    int nbid = (orig & 7) * 64 + (orig >> 3);
    int bh = nbid >> 5;
    int qt = nbid & 31;
    int q0 = qt * 128 + qw * 64;
    int khbase = half * 2048;

    __bf16* Kst = smem + half * 8192;          // [2][2048] dbuf
    __bf16* Vst = smem + half * 8192 + 4096;   // [2][2048] dbuf

    const __hip_bfloat16* Qh = Qb + (size_t)bh * NN * DH;
    const __hip_bfloat16* Kh = Kb + (size_t)bh * NN * DH;
    const __hip_bfloat16* Vh = Vt + (size_t)bh * DH * NN;

    // Q as B-operand (loop-invariant): 4 q-frags x 2 k-chunks
    bf16x8 bq[4][2];
    #pragma unroll
    for (int qf = 0; qf < 4; qf++)
        #pragma unroll
        for (int kc = 0; kc < 2; kc++)
            bq[qf][kc] = *(const bf16x8*)(Qh + (size_t)(q0 + qf * 16 + lane16) * DH + kc * 32 + quad * 8);

    // staging maps: this wave stages its half's FULL tiles.
    // K tile 32x64 (8 granules/row, kswz); V tile 64x32 (4 granules/row, swz)
    int kgo[4], vgo[4], sbase[4];
    #pragma unroll
    for (int j = 0; j < 4; j++) {
        int p = j * 64 + lane;
        int gk = kswz(p);
        kgo[j] = (gk >> 3) * DH + (gk & 7) * 8;
        int gv = swz(p);
        vgo[j] = (gv >> 2) * NN + (gv & 3) * 8;
        sbase[j] = j * 512;
    }
    // K A-frag offsets with key permutation sigma (32-key restriction)
    int koff[2][2];
    #pragma unroll
    for (int kf = 0; kf < 2; kf++) {
        int key = (lane16 >> 2) * 8 + 4 * kf + (lane16 & 3);
        #pragma unroll
        for (int kc = 0; kc < 2; kc++)
            koff[kf][kc] = kswz(key * 8 + kc * 4 + quad) * 8;
    }
    // V A-frag offsets: row d=dt*16+lane16, keys quad*8..+7
    int voff[4];
    #pragma unroll
    for (int dt = 0; dt < 4; dt++)
        voff[dt] = swz((dt * 16 + lane16) * 4 + quad) * 8;

    for (int j = 0; j < 4; j++) {
        gl_lds16(Kh + (size_t)khbase * DH + kgo[j], &Kst[sbase[j]]);
        gl_lds16(Vh + khbase + vgo[j], &Vst[sbase[j]]);
    }
    __syncthreads();

    bf16x8 ones8;
    #pragma unroll
    for (int j = 0; j < 8; j++) ones8[j] = (__bf16)1.0f;
    f32x4 o[4][4] = {};    // O^T[d-frag dt][q-frag qf]
    f32x4 ol[4] = {};      // l[q]

    for (int it = 0; it < 64; ++it) {
        int cur = it & 1, nb = cur ^ 1;
        int k1 = khbase + ((it + 1) & 63) * 32;   // wraps on last iter (harmless)
        for (int j = 0; j < 4; j++) {
            gl_lds16(Kh + (size_t)k1 * DH + kgo[j], &Kst[nb * 2048 + sbase[j]]);
            gl_lds16(Vh + k1 + vgo[j], &Vst[nb * 2048 + sbase[j]]);
        }

        // ---- S^T = K Q^T : 32 keys (sigma-ordered) x 64 q ----
        bf16x8 ka[2][2];
        #pragma unroll
        for (int kf = 0; kf < 2; kf++)
            #pragma unroll
            for (int kc = 0; kc < 2; kc++)
                ka[kf][kc] = *(const bf16x8*)&Kst[cur * 2048 + koff[kf][kc]];
        f32x4 s[2][4];
        #pragma unroll
        for (int kf = 0; kf < 2; kf++)
            #pragma unroll
            for (int qf = 0; qf < 4; qf++) {
                f32x4 t = {};
                t = mfma32(ka[kf][0], bq[qf][0], t);
                t = mfma32(ka[kf][1], bq[qf][1], t);
                s[kf][qf] = t;
            }

        // ---- P^T = exp2(S^T), straight to bf16 registers ----
        bf16x4 pt[2][4];
        #pragma unroll
        for (int kf = 0; kf < 2; kf++)
            #pragma unroll
            for (int qf = 0; qf < 4; qf++)
                #pragma unroll
                for (int r = 0; r < 4; r++)
                    pt[kf][qf][r] = (__bf16)__builtin_amdgcn_exp2f(s[kf][qf][r]);

        // ---- O^T += V^T P^T ; B-frag = register concat of the 2 C-frags ----
        bf16x8 av[4];
        #pragma unroll
        for (int dt = 0; dt < 4; dt++)
            av[dt] = *(const bf16x8*)&Vst[cur * 2048 + voff[dt]];
        #pragma unroll
        for (int qf = 0; qf < 4; qf++) {
            bf16x8 pb = __builtin_shufflevector(pt[0][qf], pt[1][qf],
                                                0, 1, 2, 3, 4, 5, 6, 7);
            #pragma unroll
            for (int dt = 0; dt < 4; dt++)
                o[dt][qf] = mfma32(av[dt], pb, o[dt][qf]);
            ol[qf] = mfma32(ones8, pb, ol[qf]);
        }

        __syncthreads();   // drains next-tile DMA; protects cur buf reuse
    }

    // ---- epilogue: cross-half combine in LDS, then normalized store --------
    // All DMA drained by the loop's final barrier; smem is reusable.
    float* Osh = (float*)smem;            // [128][68] f32, pad 68
    float* lsh = Osh + 128 * 68;          // [128]
    if (half == 1) {
        #pragma unroll
        for (int qf = 0; qf < 4; qf++) {
            #pragma unroll
            for (int dt = 0; dt < 4; dt++)
                *(f32x4*)&Osh[(qw * 64 + qf * 16 + lane16) * 68 + dt * 16 + quad * 4] = o[dt][qf];
            if (quad == 0) lsh[qw * 64 + qf * 16 + lane16] = ol[qf][0];
        }
    }
    __syncthreads();
    if (half == 0) {
        // epi region starts past Osh+lsh (35328 B -> bf16 index 17664)
        __bf16* epi = smem + 17664 + qw * 4096;
        #pragma unroll
        for (int qf = 0; qf < 4; qf++) {
            float l = ol[qf][0] + lsh[qw * 64 + qf * 16 + lane16];
            float rinv = 1.0f / l;
            #pragma unroll
            for (int dt = 0; dt < 4; dt++) {
                f32x4 po = *(const f32x4*)&Osh[(qw * 64 + qf * 16 + lane16) * 68 + dt * 16 + quad * 4];
                #pragma unroll
                for (int r = 0; r < 4; r++) {
                    int d = dt * 16 + quad * 4 + r;
                    int row = qf * 16 + lane16;
                    epi[swz(row * 8 + (d >> 3)) * 8 + (d & 7)] = (__bf16)((o[dt][qf][r] + po[r]) * rinv);
                }
            }
        }
        int bidx = bh >> 3, h = bh & 7;
        for (int p = 0; p < 8; p++) {
            int row = p * 8 + (lane >> 3), mc = lane & 7;
            bf16x8 vv = *(const bf16x8*)&epi[swz(row * 8 + mc) * 8];
            size_t base = ((size_t)bidx * NN + q0 + row) * DIM + h * 64 + mc * 8;
            if (bfmode) {
                *(bf16x8*)((__hip_bfloat16*)OutV + base) = vv;
            } else {
                float* op = (float*)OutV + base;
                f32x4 f0, f1;
                for (int j = 0; j < 4; j++) { f0[j] = (float)vv[j]; f1[j] = (float)vv[4 + j]; }
                *(f32x4*)op = f0;
                *(f32x4*)(op + 4) = f1;
            }
        }
    }
}

extern "C" void kernel_launch(void* const* d_in, const int* in_sizes, int n_in,
                              void* d_out, int out_size, void* d_ws, size_t ws_size,
                              hipStream_t stream) {
    char* ws = (char*)d_ws;
    __hip_bfloat16* Qb = (__hip_bfloat16*)ws;
    __hip_bfloat16* Kb = Qb + (size_t)BB * NH * NN * DH;
    __hip_bfloat16* Vt = Kb + (size_t)BB * NH * NN * DH;
    __hip_bfloat16* WT = Vt + (size_t)BB * NH * NN * DH;
    __hip_bfloat16* Xb = WT + (size_t)NC * DIM;
    float* Bf = (float*)(Xb + (size_t)MM * DIM);

    prep_kernel<<<2048 + 192 + 6, 256, 0, stream>>>(d_in[0], d_in[1], d_in[2], Xb, WT, Bf);
    qkv_gemm<<<(MM / 128) * (NC / 128), 256, 0, stream>>>(
        (const unsigned short*)d_in[0], Xb, WT, Bf, Qb, Kb, Vt);
    attn_fused<<<512, 256, 0, stream>>>(Qb, Kb, Vt, d_out, (const unsigned short*)d_in[0]);
}

// Round 6
// 163.634 us; speedup vs baseline: 1.5735x; 1.0767x over previous
//
#include <hip/hip_runtime.h>
#include <hip/hip_bf16.h>
#include <math.h>

#define BB    2
#define NN    4096
#define DIM   512
#define NH    8
#define DH    64
#define NC    1536   // 3*DIM
#define MM    (BB*NN) // 8192

typedef __bf16 bf16x8 __attribute__((ext_vector_type(8)));
typedef __bf16 bf16x4 __attribute__((ext_vector_type(4)));
typedef float  f32x4  __attribute__((ext_vector_type(4)));

#define QSCALE 0.18033688011112042f   // 1/sqrt(64) * log2(e)

__device__ __forceinline__ int swz(int c) { return c ^ (((c >> 3) ^ (c >> 6)) & 7); }
// K-tile swizzle: puts a lane-varying key bit into bank-bit2 (read pattern
// key=(l>>2)*8+4kf+(l&3) made the old swz bit2 lane-invariant -> 2x bank alias).
__device__ __forceinline__ int kswz(int g) { return g ^ ((g >> 3) & 3) ^ (((g >> 6) & 1) << 2); }

__device__ __forceinline__ void gl_lds16(const __hip_bfloat16* g, __bf16* l) {
    __builtin_amdgcn_global_load_lds(
        (const __attribute__((address_space(1))) unsigned int*)g,
        (__attribute__((address_space(3))) unsigned int*)l, 16, 0, 0);
}

__device__ __forceinline__ int sniff(const unsigned short* x) {
    unsigned short v = x[2 * (threadIdx.x & 63)];
    int e = (v >> 7) & 0xFF;
    unsigned long long m = __ballot(e >= 110 && e <= 140);
    return __popcll(m) >= 48;
}

__device__ __forceinline__ f32x4 mfma32(bf16x8 a, bf16x8 b, f32x4 c) {
    return __builtin_amdgcn_mfma_f32_16x16x32_bf16(a, b, c, 0, 0, 0);
}

// ---------------- prep: X->bf16 (fp32 mode only), W->WT tiled transpose, bias->f32
__global__ __launch_bounds__(256) void prep_kernel(
    const void* __restrict__ xin, const void* __restrict__ win,
    const void* __restrict__ bin,
    __hip_bfloat16* __restrict__ Xb, __hip_bfloat16* __restrict__ WT,
    float* __restrict__ Bf)
{
    __shared__ __bf16 tile[64][68];
    int bfmode = sniff((const unsigned short*)xin);
    int bid = blockIdx.x;
    int t = threadIdx.x;
    if (bid < 2048) {
        if (bfmode) return;
        int i = (bid * 256 + t) * 8;
        const float* xf = (const float*)xin + i;
        bf16x8 v;
        for (int j = 0; j < 8; j++) v[j] = (__bf16)xf[j];
        *(bf16x8*)(Xb + i) = v;
    } else if (bid < 2048 + 192) {
        int tl = bid - 2048;
        int kt = tl / 24, nt = tl % 24;
        int tx = t & 63, tyq = t >> 6;
        for (int r = 0; r < 16; r++) {
            int kl = r * 4 + tyq;
            int gi = (kt * 64 + kl) * NC + nt * 64 + tx;
            float v = bfmode ? __bfloat162float(((const __hip_bfloat16*)win)[gi])
                             : ((const float*)win)[gi];
            tile[kl][tx] = (__bf16)v;
        }
        __syncthreads();
        for (int r = 0; r < 16; r++) {
            int nl = r * 4 + tyq;
            WT[(size_t)(nt * 64 + nl) * DIM + kt * 64 + tx] = (__hip_bfloat16)(float)tile[tx][nl];
        }
    } else {
        int i = (bid - 2048 - 192) * 256 + t;
        if (i < NC)
            Bf[i] = bfmode ? __bfloat162float(((const __hip_bfloat16*)bin)[i])
                           : ((const float*)bin)[i];
    }
}

// ---------------- QKV GEMM (unchanged) ----------------
__global__ __launch_bounds__(256, 3) void qkv_gemm(
    const unsigned short* __restrict__ xs,
    const __hip_bfloat16* __restrict__ Xb,
    const __hip_bfloat16* __restrict__ WT,
    const float* __restrict__ Bf,
    __hip_bfloat16* __restrict__ Qb,
    __hip_bfloat16* __restrict__ Kb,
    __hip_bfloat16* __restrict__ Vt)
{
    __shared__ __align__(16) __bf16 smem[16384];
    __bf16* Xs = smem;
    __bf16* Ws = smem + 8192;

    int bfmode = sniff(xs);
    const __hip_bfloat16* X = bfmode ? (const __hip_bfloat16*)xs : Xb;

    int wave = threadIdx.x >> 6, lane = threadIdx.x & 63;
    int lane16 = lane & 15, quad = lane >> 4;
    int bm = blockIdx.x / 12, bn = blockIdx.x % 12;
    int m0b = bm * 128, n0b = bn * 128;
    int wm = wave >> 1, wn = wave & 1;
    int m0 = m0b + wm * 64, n0 = n0b + wn * 64;

    int xgo[2], sbase[2];
    for (int j = 0; j < 2; j++) {
        int p = (wave * 2 + j) * 64 + lane;
        int g = swz(p);
        xgo[j] = (g >> 2) * DIM + (g & 3) * 8;
        sbase[j] = (wave * 2 + j) * 512;
    }
    int aoff[4], boff[4];
    for (int mi = 0; mi < 4; mi++)
        aoff[mi] = swz((wm * 64 + mi * 16 + lane16) * 4 + quad) * 8;
    for (int ni = 0; ni < 4; ni++)
        boff[ni] = swz((wn * 64 + ni * 16 + lane16) * 4 + quad) * 8;

    const __hip_bfloat16* Xg = X  + (size_t)m0b * DIM;
    const __hip_bfloat16* Wg = WT + (size_t)n0b * DIM;

    for (int j = 0; j < 2; j++) {
        gl_lds16(Xg + xgo[j], &Xs[sbase[j]]);
        gl_lds16(Wg + xgo[j], &Ws[sbase[j]]);
    }
    __syncthreads();

    f32x4 acc[4][4] = {};
    for (int k0 = 0; k0 < DIM; k0 += 32) {
        int cur = (k0 >> 5) & 1, nbuf = cur ^ 1;
        int k1 = (k0 + 32) & (DIM - 1);
        for (int j = 0; j < 2; j++) {
            gl_lds16(Xg + k1 + xgo[j], &Xs[nbuf * 4096 + sbase[j]]);
            gl_lds16(Wg + k1 + xgo[j], &Ws[nbuf * 4096 + sbase[j]]);
        }
        bf16x8 a[4], b[4];
        for (int mi = 0; mi < 4; mi++) a[mi] = *(const bf16x8*)&Xs[cur * 4096 + aoff[mi]];
        for (int ni = 0; ni < 4; ni++) b[ni] = *(const bf16x8*)&Ws[cur * 4096 + boff[ni]];
        for (int mi = 0; mi < 4; mi++)
            for (int ni = 0; ni < 4; ni++)
                acc[mi][ni] = mfma32(a[mi], b[ni], acc[mi][ni]);
        __syncthreads();
    }
    __bf16* epi = smem + wave * 4096;

    int sec = n0b >> 9;
    int bidx = m0b >> 12;
    if (sec == 1) {
        for (int ni = 0; ni < 4; ni++) {
            int nloc = ni * 16 + lane16;
            float bv = Bf[n0 + nloc];
            for (int mi = 0; mi < 4; mi++) {
                bf16x4 pk;
                for (int r = 0; r < 4; r++) pk[r] = (__bf16)(acc[mi][ni][r] + bv);
                int idx = swz(nloc * 8 + mi * 2 + (quad >> 1)) * 8 + (quad & 1) * 4;
                *(bf16x4*)&epi[idx] = pk;
            }
        }
        int hl = (n0 - 512) >> 6;
        int mbase = m0b - bidx * NN + wm * 64;
        for (int p = 0; p < 8; p++) {
            int n = p * 8 + (lane >> 3), mc = lane & 7;
            bf16x8 vv = *(const bf16x8*)&epi[swz(n * 8 + mc) * 8];
            *(bf16x8*)(Vt + ((size_t)(bidx * 8 + hl) * 64 + n) * NN + mbase + mc * 8) = vv;
        }
    } else {
        bool isQ = (sec == 0);
        int h = (n0 & 511) >> 6;
        for (int mi = 0; mi < 4; mi++) {
            for (int ni = 0; ni < 4; ni++) {
                float bv = Bf[n0 + ni * 16 + lane16];
                int dl = ni * 16 + lane16;
                for (int r = 0; r < 4; r++) {
                    int row = mi * 16 + quad * 4 + r;
                    float v = acc[mi][ni][r] + bv;
                    if (isQ) v *= QSCALE;
                    epi[swz(row * 8 + (dl >> 3)) * 8 + (dl & 7)] = (__bf16)v;
                }
            }
        }
        __hip_bfloat16* dst = isQ ? Qb : Kb;
        int bh = bidx * 8 + h;
        int mbase = m0 - bidx * NN;
        for (int p = 0; p < 8; p++) {
            int row = p * 8 + (lane >> 3), dc = lane & 7;
            bf16x8 vv = *(const bf16x8*)&epi[swz(row * 8 + dc) * 8];
            *(bf16x8*)(dst + ((size_t)bh * NN + mbase + row) * DH + dc * 8) = vv;
        }
    }
}

// ---------------- Fused attention: 64 q/wave, key-split x2, counted vmcnt ---
// Block = 128 q x 4096 keys, 4 waves (half = key half, qw = 64-q subtile).
// T3/T4: triple-buffered K/V per half, staging SPLIT between sibling waves
// (4 gl_lds/wave/step, no duplication), raw s_barrier + counted
// s_waitcnt vmcnt(4) -- the current step's 4 DMAs stay in flight across the
// barrier; data read at step i was issued at step i-2 and is drained by the
// end-of-step-(i-1) wait+barrier. Never vmcnt(0) inside the loop.
// Prologue drains vmcnt(0) once: bq Q-loads may interleave with staging
// issues, so a counted prologue wait could leave tile-0 DMAs outstanding.
// T5: s_setprio(1) around the two MFMA clusters (phase-split makes it pay).
__global__ __launch_bounds__(256, 2) void attn_fused(
    const __hip_bfloat16* __restrict__ Qb,   // [16][4096][64], pre-scaled
    const __hip_bfloat16* __restrict__ Kb,   // [16][4096][64]
    const __hip_bfloat16* __restrict__ Vt,   // [16][64][4096]
    void* __restrict__ OutV,                 // [2][4096][512] bf16 or fp32
    const unsigned short* __restrict__ xs)
{
    // loop: [half][ K 3x2048 | V 3x2048 ] = 24576 elems (48 KB)
    // epilogue overlay: Osh 128x68 f32 + lsh 128 f32 + epi 2x4096 bf16
    __shared__ __align__(16) __bf16 smem[26624];   // 53.25 KB

    int bfmode = sniff(xs);
    int wave = threadIdx.x >> 6, lane = threadIdx.x & 63;
    int lane16 = lane & 15, quad = lane >> 4;
    int half = wave >> 1, qw = wave & 1;

    // XCD swizzle: 512 blocks, 64 per XCD = 2 whole heads per XCD L2.
    int orig = blockIdx.x;
    int nbid = (orig & 7) * 64 + (orig >> 3);
    int bh = nbid >> 5;
    int qt = nbid & 31;
    int q0 = qt * 128 + qw * 64;
    int khbase = half * 2048;

    __bf16* Kst = smem + half * 12288;   // [3][2048]
    __bf16* Vst = Kst + 6144;            // [3][2048]

    const __hip_bfloat16* Qh = Qb + (size_t)bh * NN * DH;
    const __hip_bfloat16* Kh = Kb + (size_t)bh * NN * DH;
    const __hip_bfloat16* Vh = Vt + (size_t)bh * DH * NN;

    // Q as B-operand (loop-invariant): 4 q-frags x 2 k-chunks
    bf16x8 bq[4][2];
    #pragma unroll
    for (int qf = 0; qf < 4; qf++)
        #pragma unroll
        for (int kc = 0; kc < 2; kc++)
            bq[qf][kc] = *(const bf16x8*)(Qh + (size_t)(q0 + qf * 16 + lane16) * DH + kc * 32 + quad * 8);

    // staging maps, SPLIT between sibling waves: wave qw stages granule-sets
    // {2qw, 2qw+1} of each 32x64 K tile (kswz) and 64x32 V tile (swz).
    int kgo[2], vgo[2], sbase[2];
    #pragma unroll
    for (int j = 0; j < 2; j++) {
        int p = (qw * 2 + j) * 64 + lane;
        int gk = kswz(p);
        kgo[j] = (gk >> 3) * DH + (gk & 7) * 8;
        int gv = swz(p);
        vgo[j] = (gv >> 2) * NN + (gv & 3) * 8;
        sbase[j] = (qw * 2 + j) * 512;
    }
    // K A-frag offsets with key permutation sigma (32-key restriction)
    int koff[2][2];
    #pragma unroll
    for (int kf = 0; kf < 2; kf++) {
        int key = (lane16 >> 2) * 8 + 4 * kf + (lane16 & 3);
        #pragma unroll
        for (int kc = 0; kc < 2; kc++)
            koff[kf][kc] = kswz(key * 8 + kc * 4 + quad) * 8;
    }
    // V A-frag offsets: row d=dt*16+lane16, keys quad*8..+7
    int voff[4];
    #pragma unroll
    for (int dt = 0; dt < 4; dt++)
        voff[dt] = swz((dt * 16 + lane16) * 4 + quad) * 8;

    // prologue: stage tiles 0 and 1 into bufs 0,1 (8 DMAs this wave), then a
    // ONE-TIME full drain (robust against bq/staging issue-order mixing).
    #pragma unroll
    for (int t = 0; t < 2; t++) {
        int kt = khbase + t * 32;
        #pragma unroll
        for (int j = 0; j < 2; j++) {
            gl_lds16(Kh + (size_t)kt * DH + kgo[j], &Kst[t * 2048 + sbase[j]]);
            gl_lds16(Vh + kt + vgo[j], &Vst[t * 2048 + sbase[j]]);
        }
    }
    asm volatile("s_waitcnt vmcnt(0)" ::: "memory");
    __builtin_amdgcn_sched_barrier(0);
    __builtin_amdgcn_s_barrier();
    __builtin_amdgcn_sched_barrier(0);

    bf16x8 ones8;
    #pragma unroll
    for (int j = 0; j < 8; j++) ones8[j] = (__bf16)1.0f;
    f32x4 o[4][4] = {};    // O^T[d-frag dt][q-frag qf]
    f32x4 ol[4] = {};      // l[q]

    int cur = 0, pf = 2;
    for (int it = 0; it < 64; ++it) {
        // prefetch tile it+2 into buf pf (wraps harmlessly on last 2 iters;
        // WAR on pf safe: pf was read at step it-1, drained by that step's
        // lgkmcnt(0)+barrier before these issues)
        int kt = khbase + ((it + 2) & 63) * 32;
        #pragma unroll
        for (int j = 0; j < 2; j++) {
            gl_lds16(Kh + (size_t)kt * DH + kgo[j], &Kst[pf * 2048 + sbase[j]]);
            gl_lds16(Vh + kt + vgo[j], &Vst[pf * 2048 + sbase[j]]);
        }

        // ds_reads of buf cur (ready: issued at step it-2, drained end it-1)
        bf16x8 ka[2][2];
        #pragma unroll
        for (int kf = 0; kf < 2; kf++)
            #pragma unroll
            for (int kc = 0; kc < 2; kc++)
                ka[kf][kc] = *(const bf16x8*)&Kst[cur * 2048 + koff[kf][kc]];
        bf16x8 av[4];
        #pragma unroll
        for (int dt = 0; dt < 4; dt++)
            av[dt] = *(const bf16x8*)&Vst[cur * 2048 + voff[dt]];

        // ---- S^T = K Q^T : 32 keys (sigma-ordered) x 64 q ----
        f32x4 s[2][4];
        __builtin_amdgcn_s_setprio(1);
        #pragma unroll
        for (int kf = 0; kf < 2; kf++)
            #pragma unroll
            for (int qf = 0; qf < 4; qf++) {
                f32x4 t = {};
                t = mfma32(ka[kf][0], bq[qf][0], t);
                t = mfma32(ka[kf][1], bq[qf][1], t);
                s[kf][qf] = t;
            }
        __builtin_amdgcn_s_setprio(0);

        // ---- P^T = exp2(S^T), straight to bf16 registers ----
        bf16x4 pt[2][4];
        #pragma unroll
        for (int kf = 0; kf < 2; kf++)
            #pragma unroll
            for (int qf = 0; qf < 4; qf++)
                #pragma unroll
                for (int r = 0; r < 4; r++)
                    pt[kf][qf][r] = (__bf16)__builtin_amdgcn_exp2f(s[kf][qf][r]);

        // ---- O^T += V^T P^T ; B-frag = register concat of the 2 C-frags ----
        __builtin_amdgcn_s_setprio(1);
        #pragma unroll
        for (int qf = 0; qf < 4; qf++) {
            bf16x8 pb = __builtin_shufflevector(pt[0][qf], pt[1][qf],
                                                0, 1, 2, 3, 4, 5, 6, 7);
            #pragma unroll
            for (int dt = 0; dt < 4; dt++)
                o[dt][qf] = mfma32(av[dt], pb, o[dt][qf]);
            ol[qf] = mfma32(ones8, pb, ol[qf]);
        }
        __builtin_amdgcn_s_setprio(0);

        // counted sync: my step-(it-1) DMAs drained (4 current stay in
        // flight); lgkmcnt(0) = my ds_reads done -> barrier makes both
        // conditions mutual across all 4 waves.
        asm volatile("s_waitcnt vmcnt(4) lgkmcnt(0)" ::: "memory");
        __builtin_amdgcn_sched_barrier(0);
        __builtin_amdgcn_s_barrier();
        __builtin_amdgcn_sched_barrier(0);

        cur = (cur == 2) ? 0 : cur + 1;
        pf  = (pf  == 2) ? 0 : pf + 1;
    }

    // full drain before smem reuse (wrapped prefetches may still be in flight)
    asm volatile("s_waitcnt vmcnt(0) lgkmcnt(0)" ::: "memory");
    __builtin_amdgcn_sched_barrier(0);
    __builtin_amdgcn_s_barrier();
    __builtin_amdgcn_sched_barrier(0);

    // ---- epilogue: cross-half combine in LDS, then normalized store --------
    float* Osh = (float*)smem;            // [128][68] f32, pad 68
    float* lsh = Osh + 128 * 68;          // [128]
    if (half == 1) {
        #pragma unroll
        for (int qf = 0; qf < 4; qf++) {
            #pragma unroll
            for (int dt = 0; dt < 4; dt++)
                *(f32x4*)&Osh[(qw * 64 + qf * 16 + lane16) * 68 + dt * 16 + quad * 4] = o[dt][qf];
            if (quad == 0) lsh[qw * 64 + qf * 16 + lane16] = ol[qf][0];
        }
    }
    __syncthreads();
    if (half == 0) {
        // epi region starts past Osh+lsh (35328 B -> bf16 index 17664)
        __bf16* epi = smem + 17664 + qw * 4096;
        #pragma unroll
        for (int qf = 0; qf < 4; qf++) {
            float l = ol[qf][0] + lsh[qw * 64 + qf * 16 + lane16];
            float rinv = 1.0f / l;
            #pragma unroll
            for (int dt = 0; dt < 4; dt++) {
                f32x4 po = *(const f32x4*)&Osh[(qw * 64 + qf * 16 + lane16) * 68 + dt * 16 + quad * 4];
                #pragma unroll
                for (int r = 0; r < 4; r++) {
                    int d = dt * 16 + quad * 4 + r;
                    int row = qf * 16 + lane16;
                    epi[swz(row * 8 + (d >> 3)) * 8 + (d & 7)] = (__bf16)((o[dt][qf][r] + po[r]) * rinv);
                }
            }
        }
        int bidx = bh >> 3, h = bh & 7;
        for (int p = 0; p < 8; p++) {
            int row = p * 8 + (lane >> 3), mc = lane & 7;
            bf16x8 vv = *(const bf16x8*)&epi[swz(row * 8 + mc) * 8];
            size_t base = ((size_t)bidx * NN + q0 + row) * DIM + h * 64 + mc * 8;
            if (bfmode) {
                *(bf16x8*)((__hip_bfloat16*)OutV + base) = vv;
            } else {
                float* op = (float*)OutV + base;
                f32x4 f0, f1;
                for (int j = 0; j < 4; j++) { f0[j] = (float)vv[j]; f1[j] = (float)vv[4 + j]; }
                *(f32x4*)op = f0;
                *(f32x4*)(op + 4) = f1;
            }
        }
    }
}

extern "C" void kernel_launch(void* const* d_in, const int* in_sizes, int n_in,
                              void* d_out, int out_size, void* d_ws, size_t ws_size,
                              hipStream_t stream) {
    char* ws = (char*)d_ws;
    __hip_bfloat16* Qb = (__hip_bfloat16*)ws;
    __hip_bfloat16* Kb = Qb + (size_t)BB * NH * NN * DH;
    __hip_bfloat16* Vt = Kb + (size_t)BB * NH * NN * DH;
    __hip_bfloat16* WT = Vt + (size_t)BB * NH * NN * DH;
    __hip_bfloat16* Xb = WT + (size_t)NC * DIM;
    float* Bf = (float*)(Xb + (size_t)MM * DIM);

    prep_kernel<<<2048 + 192 + 6, 256, 0, stream>>>(d_in[0], d_in[1], d_in[2], Xb, WT, Bf);
    qkv_gemm<<<(MM / 128) * (NC / 128), 256, 0, stream>>>(
        (const unsigned short*)d_in[0], Xb, WT, Bf, Qb, Kb, Vt);
    attn_fused<<<512, 256, 0, stream>>>(Qb, Kb, Vt, d_out, (const unsigned short*)d_in[0]);
}